// Round 10
// baseline (245.766 us; speedup 1.0000x reference)
//
#include <hip/hip_runtime.h>

#define AS1 __attribute__((address_space(1)))
#define AS3 __attribute__((address_space(3)))

typedef float __attribute__((ext_vector_type(4))) f32x4;
typedef unsigned int __attribute__((ext_vector_type(2))) u32x2;
typedef int __attribute__((ext_vector_type(4))) i32x4;
typedef int __attribute__((ext_vector_type(8))) i32x8;

#define M_DIM 65536
#define N_DIM 1024
#define K_DIM 1024

#define BM 256
#define BN 256
#define BK 128

#define WS_NEEDED ((size_t)M_DIM * K_DIM + (size_t)K_DIM * N_DIM)  // A8 64MB + W8 1MB
#define SCALE_ONE 0x7F7F7F7F  // e8m0 127 = 2^0 in every byte -> scale 1.0 for any opsel

// pack 4 floats -> 4 fp8 e4m3 bytes (RNE, OCP on gfx950)
__device__ inline unsigned int cvt4(float f0, float f1, float f2, float f3) {
    int r = __builtin_amdgcn_cvt_pk_fp8_f32(f0, f1, 0, false);   // bytes 0,1
    r = __builtin_amdgcn_cvt_pk_fp8_f32(f2, f3, r, true);        // bytes 2,3
    return (unsigned int)r;
}

// ---------------- pass 1a: A f32 -> fp8 row-major ----------------
__global__ __launch_bounds__(256) void quant_a_kernel(const float* __restrict__ in,
                                                      unsigned char* __restrict__ out) {
    const int total8 = (M_DIM * K_DIM) / 8;          // 8388608
    const int stride = 2048 * 256;
    for (int i = blockIdx.x * 256 + threadIdx.x; i < total8; i += stride) {
        const float* p = in + (size_t)i * 8;
        const f32x4 v0 = *(const f32x4*)p;
        const f32x4 v1 = *(const f32x4*)(p + 4);
        u32x2 r;
        r.x = cvt4(v0[0], v0[1], v0[2], v0[3]);
        r.y = cvt4(v1[0], v1[1], v1[2], v1[3]);
        ((u32x2*)out)[i] = r;
    }
}

// ---------------- pass 1b: W f32 -> fp8 packed [K/16][N][16] ----------------
// out[(t*N + n)*16 + s] = fp8(W[t*16 + s][n])
__global__ __launch_bounds__(256) void quant_w_kernel(const float* __restrict__ w,
                                                      unsigned char* __restrict__ out) {
    const int idx = blockIdx.x * 256 + threadIdx.x;  // 0..65535
    const int t = idx >> 10, n = idx & 1023;
    const float* wp = w + (size_t)(t * 16) * N_DIM + n;
    unsigned int r[4];
#pragma unroll
    for (int q = 0; q < 4; ++q) {
        float f0 = wp[(size_t)(q * 4 + 0) * N_DIM];
        float f1 = wp[(size_t)(q * 4 + 1) * N_DIM];
        float f2 = wp[(size_t)(q * 4 + 2) * N_DIM];
        float f3 = wp[(size_t)(q * 4 + 3) * N_DIM];
        r[q] = cvt4(f0, f1, f2, f3);
    }
    i32x4 v; v.x = (int)r[0]; v.y = (int)r[1]; v.z = (int)r[2]; v.w = (int)r[3];
    ((i32x4*)out)[idx] = v;
}

// ---------------- pass 2: MX-fp8 GEMM, 256x256, 8 waves, dbuf issue-early ----------------
// C[M,N] = f32(fp16_round(A8 @ W8 * scale_b)). BK=128, one K=128 MFMA per fragment.
// Pipeline: STAGE(t+1) issued BEFORE compute(t); __syncthreads() (drains vmcnt+lgkm)
// after compute releases buf[t&1] and publishes buf[(t+1)&1]. One barrier per K-step.
// LDS A: rows of 128B, 16B-unit XOR(row&7) swizzle (applied on the global source).
// LDS B: [tt=k/16][n 0..255][16] linear (source contiguous after packing).
__global__ __launch_bounds__(512) void gemm_fp8_kernel(const unsigned char* __restrict__ A8,
                                                       const unsigned char* __restrict__ B8,
                                                       const float* __restrict__ scale_b,
                                                       float* __restrict__ out) {
    __shared__ __attribute__((aligned(16))) unsigned char sA[2][BM * BK];  // 2 x 32 KB
    __shared__ __attribute__((aligned(16))) unsigned char sB[2][BK * BN];  // 2 x 32 KB

    const int tid = threadIdx.x;
    const int l = tid & 63;
    const int wid = tid >> 6;        // 0..7
    const int lr = l & 15;
    const int lg = l >> 4;           // k-quarter (32 elements each)
    const int wr = wid >> 2;         // wave row 0..1  (each 128 rows)
    const int wc = wid & 3;          // wave col 0..3  (each 64 cols)

    // XCD swizzle: 1024 blocks, XCD = b&7. Each XCD owns 32 consecutive m-panels;
    // the 4 n-tiles of a panel run back-to-back (A8-panel 256KB L2-resident).
    const int b = blockIdx.x;
    const int local = b >> 3;                         // 0..127
    const int m_idx = (b & 7) * 32 + (local >> 2);    // 0..255
    const int n_idx = local & 3;                      // 0..3
    const int m0 = m_idx * BM;
    const int n0 = n_idx * BN;

    f32x4 acc[8][4];
#pragma unroll
    for (int i = 0; i < 8; ++i)
#pragma unroll
        for (int j = 0; j < 4; ++j) acc[i][j] = (f32x4)0.0f;

    // A staging: chunk = 8 rows x 128B; lane l -> row l>>3, dest 16B unit l&7
    const int a_rl = l >> 3;
    const int a_u = l & 7;

    // Per-thread: 4 A-chunk + 4 B-chunk gload_lds per K-tile (64 KB / 512 / 16B).
#define STAGE(T, BUF)                                                                   \
    do {                                                                                \
        const int k0s = (T) * BK;                                                       \
        _Pragma("unroll") for (int c = 0; c < 4; ++c) {                                 \
            const int i = wid * 4 + c;              /* chunk 0..31 */                   \
            const int row = i * 8 + a_rl;           /* 0..255 */                        \
            const unsigned char* src =                                                  \
                A8 + (size_t)(m0 + row) * K_DIM + k0s + ((a_u ^ (row & 7)) * 16);       \
            __builtin_amdgcn_global_load_lds((const AS1 void*)src,                      \
                                             (AS3 void*)(sA[BUF] + i * 1024), 16, 0, 0); \
        }                                                                               \
        _Pragma("unroll") for (int c = 0; c < 4; ++c) {                                 \
            const int idx = wid * 4 + c;            /* 0..31 */                         \
            const int tt = idx >> 2, q = idx & 3;   /* k-16-group, n-quarter */         \
            const unsigned char* src =                                                  \
                B8 + ((size_t)((T) * 8 + tt) * N_DIM + n0 + q * 64) * 16 + l * 16;      \
            __builtin_amdgcn_global_load_lds((const AS1 void*)src,                      \
                                             (AS3 void*)(sB[BUF] + tt * 4096 + q * 1024), 16, 0, 0); \
        }                                                                               \
    } while (0)

    STAGE(0, 0);
    __syncthreads();   // drains vmcnt(0): buf0 ready

#pragma unroll
    for (int t = 0; t < K_DIM / BK; ++t) {
        const int cur = t & 1;
        if (t < K_DIM / BK - 1) STAGE(t + 1, cur ^ 1);  // issue early, drain late

        // ---- compute from buf[cur]: 8x4 fragments, one K=128 MFMA each ----
        i32x8 bf[4];
#pragma unroll
        for (int nj = 0; nj < 4; ++nj) {
            const int n = wc * 64 + nj * 16 + lr;
            const i32x4 b0 = *(const i32x4*)(sB[cur] + (lg * 2 + 0) * 4096 + n * 16);
            const i32x4 b1 = *(const i32x4*)(sB[cur] + (lg * 2 + 1) * 4096 + n * 16);
            bf[nj] = __builtin_shufflevector(b0, b1, 0, 1, 2, 3, 4, 5, 6, 7);
        }
#pragma unroll
        for (int mi = 0; mi < 8; ++mi) {
            const int r = wr * 128 + mi * 16 + lr;
            const i32x4 a0 = *(const i32x4*)(sA[cur] + r * 128 + (((2 * lg + 0) ^ (r & 7)) * 16));
            const i32x4 a1 = *(const i32x4*)(sA[cur] + r * 128 + (((2 * lg + 1) ^ (r & 7)) * 16));
            const i32x8 af = __builtin_shufflevector(a0, a1, 0, 1, 2, 3, 4, 5, 6, 7);
#pragma unroll
            for (int nj = 0; nj < 4; ++nj)
                acc[mi][nj] = __builtin_amdgcn_mfma_scale_f32_16x16x128_f8f6f4(
                    af, bf[nj], acc[mi][nj], 0, 0,        // cbsz=fp8, blgp=fp8
                    0, SCALE_ONE, 0, SCALE_ONE);          // opsel/scale A, opsel/scale B
        }
        __syncthreads();   // drains t+1's loads (hidden under compute) + releases buf[cur]
    }
#undef STAGE

    // ---- epilogue: scale, round through fp16, store f32 ----
    // C/D layout (shape-determined): col = lane&15, row = (lane>>4)*4 + reg
#pragma unroll
    for (int nj = 0; nj < 4; ++nj) {
        const int col = n0 + wc * 64 + nj * 16 + lr;
        const float sc = scale_b[col];
#pragma unroll
        for (int mi = 0; mi < 8; ++mi) {
            const int row = m0 + wr * 128 + mi * 16 + lg * 4;
#pragma unroll
            for (int r = 0; r < 4; ++r) {
                const float v = acc[mi][nj][r] * sc;
                out[(size_t)(row + r) * N_DIM + col] = (float)(_Float16)v;
            }
        }
    }
}

// ---------------- fallback: round-6 fused kernel (passing, 350 us) ----------------
__global__ __launch_bounds__(256) void gemm_fused_kernel(const float* __restrict__ A,
                                                         const float* __restrict__ W,
                                                         const float* __restrict__ scale_b,
                                                         float* __restrict__ out) {
    __shared__ __attribute__((aligned(16))) unsigned char sA[128 * 64];
    __shared__ __attribute__((aligned(16))) unsigned char sB[64 * 128];

    const int tid = threadIdx.x;
    const int l = tid & 63;
    const int wid = tid >> 6;
    const int lr = l & 15;
    const int lg = l >> 4;
    const int wr = wid >> 1;
    const int wc = wid & 1;
    const int n0 = blockIdx.x * 128;
    const int m0 = blockIdx.y * 128;

    f32x4 acc[4][4];
#pragma unroll
    for (int i = 0; i < 4; ++i)
#pragma unroll
        for (int j = 0; j < 4; ++j) acc[i][j] = (f32x4)0.0f;

    const int a_g = tid & 7;
    const int a_rb = tid >> 3;
    const int aswz = lr & 6;

    for (int kt = 0; kt < K_DIM / 64; ++kt) {
        const int k0 = kt * 64;
#pragma unroll
        for (int o = 0; o < 4; ++o) {
            const int row = o * 32 + a_rb;
            const float* ap = A + (size_t)(m0 + row) * K_DIM + k0 + a_g * 8;
            const f32x4 v0 = *(const f32x4*)ap;
            const f32x4 v1 = *(const f32x4*)(ap + 4);
            u32x2 r;
            r.x = cvt4(v0[0], v0[1], v0[2], v0[3]);
            r.y = cvt4(v1[0], v1[1], v1[2], v1[3]);
            *(u32x2*)(sA + row * 64 + ((a_g ^ (row & 6)) * 8)) = r;
        }
#pragma unroll
        for (int o = 0; o < 4; ++o) {
            const int e = o * 256 + tid;
            const int g = e >> 7;
            const int n = e & 127;
            const float* wp = W + (size_t)(k0 + g * 8) * N_DIM + n0 + n;
            float f[8];
#pragma unroll
            for (int j = 0; j < 8; ++j) f[j] = wp[(size_t)j * N_DIM];
            u32x2 r;
            r.x = cvt4(f[0], f[1], f[2], f[3]);
            r.y = cvt4(f[4], f[5], f[6], f[7]);
            *(u32x2*)(sB + g * 1024 + n * 8) = r;
        }
        __syncthreads();

#pragma unroll
        for (int kk = 0; kk < 2; ++kk) {
            long long af[4], bfr[4];
            const int gread = kk * 4 + lg;
#pragma unroll
            for (int mi = 0; mi < 4; ++mi) {
                const int m = wr * 64 + mi * 16 + lr;
                af[mi] = *(const long long*)(sA + m * 64 + ((gread ^ aswz) * 8));
            }
#pragma unroll
            for (int nj = 0; nj < 4; ++nj) {
                const int n = wc * 64 + nj * 16 + lr;
                bfr[nj] = *(const long long*)(sB + gread * 1024 + n * 8);
            }
#pragma unroll
            for (int mi = 0; mi < 4; ++mi)
#pragma unroll
                for (int nj = 0; nj < 4; ++nj)
                    acc[mi][nj] = __builtin_amdgcn_mfma_f32_16x16x32_fp8_fp8(
                        af[mi], bfr[nj], acc[mi][nj], 0, 0, 0);
        }
        __syncthreads();
    }

#pragma unroll
    for (int nj = 0; nj < 4; ++nj) {
        const int col = n0 + wc * 64 + nj * 16 + lr;
        const float sc = scale_b[col];
#pragma unroll
        for (int mi = 0; mi < 4; ++mi) {
            const int row = m0 + wr * 64 + mi * 16 + lg * 4;
#pragma unroll
            for (int r = 0; r < 4; ++r) {
                const float v = acc[mi][nj][r] * sc;
                out[(size_t)(row + r) * N_DIM + col] = (float)(_Float16)v;
            }
        }
    }
}

extern "C" void kernel_launch(void* const* d_in, const int* in_sizes, int n_in,
                              void* d_out, int out_size, void* d_ws, size_t ws_size,
                              hipStream_t stream) {
    (void)out_size;
    const void* pA = d_in[0];
    const void* pW = (n_in > 1) ? d_in[1] : d_in[0];
    const void* pS = (n_in > 2) ? d_in[2] : d_in[0];
    for (int i = 0; i < n_in && i < 3; ++i) {
        if (in_sizes[i] == M_DIM * K_DIM) pA = d_in[i];
        else if (in_sizes[i] == K_DIM * N_DIM) pW = d_in[i];
        else if (in_sizes[i] == N_DIM) pS = d_in[i];
    }
    const float* A = (const float*)pA;
    const float* W = (const float*)pW;
    const float* sb = (const float*)pS;
    float* out = (float*)d_out;

    if (ws_size >= WS_NEEDED && d_ws != nullptr) {
        unsigned char* A8 = (unsigned char*)d_ws;
        unsigned char* W8 = A8 + (size_t)M_DIM * K_DIM;
        quant_a_kernel<<<2048, 256, 0, stream>>>(A, A8);
        quant_w_kernel<<<256, 256, 0, stream>>>(W, W8);
        gemm_fp8_kernel<<<(M_DIM / BM) * (N_DIM / BN), 512, 0, stream>>>(A8, W8, sb, out);
    } else {
        gemm_fused_kernel<<<dim3(N_DIM / 128, M_DIM / 128), 256, 0, stream>>>(A, W, sb, out);
    }
}

// Round 11
// 242.235 us; speedup vs baseline: 1.0146x; 1.0146x over previous
//
#include <hip/hip_runtime.h>

#define AS1 __attribute__((address_space(1)))
#define AS3 __attribute__((address_space(3)))

typedef float __attribute__((ext_vector_type(4))) f32x4;
typedef unsigned int __attribute__((ext_vector_type(2))) u32x2;
typedef int __attribute__((ext_vector_type(4))) i32x4;
typedef int __attribute__((ext_vector_type(8))) i32x8;

#define M_DIM 65536
#define N_DIM 1024
#define K_DIM 1024

#define BM 256
#define BN 256
#define BK 128

#define WS_NEEDED ((size_t)M_DIM * K_DIM + (size_t)K_DIM * N_DIM)  // A8 64MB + W8 1MB
#define SCALE_ONE 0x7F7F7F7F  // e8m0 127 = 2^0 in every byte -> scale 1.0 for any opsel

// pack 4 floats -> 4 fp8 e4m3 bytes (RNE, OCP on gfx950)
__device__ inline unsigned int cvt4(float f0, float f1, float f2, float f3) {
    int r = __builtin_amdgcn_cvt_pk_fp8_f32(f0, f1, 0, false);   // bytes 0,1
    r = __builtin_amdgcn_cvt_pk_fp8_f32(f2, f3, r, true);        // bytes 2,3
    return (unsigned int)r;
}

// ---------------- pass 1a: A f32 -> fp8 row-major ----------------
__global__ __launch_bounds__(256) void quant_a_kernel(const float* __restrict__ in,
                                                      unsigned char* __restrict__ out) {
    const int total8 = (M_DIM * K_DIM) / 8;          // 8388608
    const int stride = 2048 * 256;
    for (int i = blockIdx.x * 256 + threadIdx.x; i < total8; i += stride) {
        const float* p = in + (size_t)i * 8;
        const f32x4 v0 = *(const f32x4*)p;
        const f32x4 v1 = *(const f32x4*)(p + 4);
        u32x2 r;
        r.x = cvt4(v0[0], v0[1], v0[2], v0[3]);
        r.y = cvt4(v1[0], v1[1], v1[2], v1[3]);
        ((u32x2*)out)[i] = r;
    }
}

// ---------------- pass 1b: W f32 -> fp8 packed [K/16][N][16] ----------------
// out[(t*N + n)*16 + s] = fp8(W[t*16 + s][n])
__global__ __launch_bounds__(256) void quant_w_kernel(const float* __restrict__ w,
                                                      unsigned char* __restrict__ out) {
    const int idx = blockIdx.x * 256 + threadIdx.x;  // 0..65535
    const int t = idx >> 10, n = idx & 1023;
    const float* wp = w + (size_t)(t * 16) * N_DIM + n;
    unsigned int r[4];
#pragma unroll
    for (int q = 0; q < 4; ++q) {
        float f0 = wp[(size_t)(q * 4 + 0) * N_DIM];
        float f1 = wp[(size_t)(q * 4 + 1) * N_DIM];
        float f2 = wp[(size_t)(q * 4 + 2) * N_DIM];
        float f3 = wp[(size_t)(q * 4 + 3) * N_DIM];
        r[q] = cvt4(f0, f1, f2, f3);
    }
    i32x4 v; v.x = (int)r[0]; v.y = (int)r[1]; v.z = (int)r[2]; v.w = (int)r[3];
    ((i32x4*)out)[idx] = v;
}

// ---------------- pass 2: MX-fp8 GEMM, 256x256, 8 waves, counted-vmcnt pipeline ----------------
// Skeleton (validated sync-correct in round 9): per K-tile
//   STAGE(t+1) ; s_waitcnt vmcnt(8)  [t's 8 loads done, t+1's 8 stay in flight]
//   s_barrier ; ds_read + MFMA (setprio 1) ; s_waitcnt lgkmcnt(0) ; s_barrier
// LDS A: rows of 128B, 16B-unit XOR(row&7) swizzle (applied on global source).
// LDS B: [tt=k/16][n 0..255][16] linear. Epilogue: LDS-staged, 128B-line coalesced.
__global__ __launch_bounds__(512) void gemm_fp8_kernel(const unsigned char* __restrict__ A8,
                                                       const unsigned char* __restrict__ B8,
                                                       const float* __restrict__ scale_b,
                                                       float* __restrict__ out) {
    __shared__ __attribute__((aligned(16))) unsigned char smem[131072];  // A:0..64K (2 buf), B:64K..128K (2 buf)

    const int tid = threadIdx.x;
    const int l = tid & 63;
    const int wid = tid >> 6;        // 0..7
    const int lr = l & 15;
    const int lg = l >> 4;           // k-quarter
    const int wr = wid >> 2;         // wave row 0..1 (128 rows each)
    const int wc = wid & 3;          // wave col 0..3 (64 cols each)

    // XCD swizzle: 1024 blocks, XCD = b&7. Each XCD owns 32 consecutive m-panels;
    // the 4 n-tiles of a panel run back-to-back (A8-panel 256KB L2-resident).
    const int b = blockIdx.x;
    const int local = b >> 3;                         // 0..127
    const int m_idx = (b & 7) * 32 + (local >> 2);    // 0..255
    const int n_idx = local & 3;                      // 0..3
    const int m0 = m_idx * BM;
    const int n0 = n_idx * BN;

    f32x4 acc[8][4];
#pragma unroll
    for (int i = 0; i < 8; ++i)
#pragma unroll
        for (int j = 0; j < 4; ++j) acc[i][j] = (f32x4)0.0f;

    // A staging: chunk = 8 rows x 128B; lane l -> row l>>3, dest 16B unit l&7
    const int a_rl = l >> 3;
    const int a_u = l & 7;

    // Per-thread: 4 A-chunk + 4 B-chunk gload_lds per K-tile = 8 (vmcnt unit).
#define STAGE(T, SAB, SBB)                                                              \
    do {                                                                                \
        const int k0s = (T) * BK;                                                       \
        _Pragma("unroll") for (int c = 0; c < 4; ++c) {                                 \
            const int i = wid * 4 + c;              /* chunk 0..31 */                   \
            const int row = i * 8 + a_rl;           /* 0..255 */                        \
            const unsigned char* src =                                                  \
                A8 + (size_t)(m0 + row) * K_DIM + k0s + ((a_u ^ (row & 7)) * 16);       \
            __builtin_amdgcn_global_load_lds((const AS1 void*)src,                      \
                                             (AS3 void*)((SAB) + i * 1024), 16, 0, 0);  \
        }                                                                               \
        _Pragma("unroll") for (int c = 0; c < 4; ++c) {                                 \
            const int idx = wid * 4 + c;            /* 0..31 */                         \
            const int tt = idx >> 2, q = idx & 3;   /* k-16-group, n-quarter */         \
            const unsigned char* src =                                                  \
                B8 + ((size_t)((T) * 8 + tt) * N_DIM + n0 + q * 64) * 16 + l * 16;      \
            __builtin_amdgcn_global_load_lds((const AS1 void*)src,                      \
                                             (AS3 void*)((SBB) + tt * 4096 + q * 1024), 16, 0, 0); \
        }                                                                               \
    } while (0)

    STAGE(0, smem, smem + 65536);

#pragma unroll
    for (int t = 0; t < K_DIM / BK; ++t) {
        const int cur = t & 1;
        const unsigned char* sAc = smem + cur * 32768;
        const unsigned char* sBc = smem + 65536 + cur * 32768;
        if (t < K_DIM / BK - 1) {
            unsigned char* sAn = smem + (cur ^ 1) * 32768;
            unsigned char* sBn = smem + 65536 + (cur ^ 1) * 32768;
            STAGE(t + 1, sAn, sBn);
            asm volatile("s_waitcnt vmcnt(8)" ::: "memory");   // t's loads landed
        } else {
            asm volatile("s_waitcnt vmcnt(0)" ::: "memory");   // final drain
        }
        __builtin_amdgcn_s_barrier();   // buf[cur] published to all waves

        // ---- compute from buf[cur]: 8x4 fragments, one K=128 MFMA each ----
        i32x8 bf[4];
#pragma unroll
        for (int nj = 0; nj < 4; ++nj) {
            const int n = wc * 64 + nj * 16 + lr;
            const i32x4 b0 = *(const i32x4*)(sBc + (lg * 2 + 0) * 4096 + n * 16);
            const i32x4 b1 = *(const i32x4*)(sBc + (lg * 2 + 1) * 4096 + n * 16);
            bf[nj] = __builtin_shufflevector(b0, b1, 0, 1, 2, 3, 4, 5, 6, 7);
        }
        __builtin_amdgcn_s_setprio(1);
#pragma unroll
        for (int mi = 0; mi < 8; ++mi) {
            const int r = wr * 128 + mi * 16 + lr;
            const i32x4 a0 = *(const i32x4*)(sAc + r * 128 + (((2 * lg + 0) ^ (r & 7)) * 16));
            const i32x4 a1 = *(const i32x4*)(sAc + r * 128 + (((2 * lg + 1) ^ (r & 7)) * 16));
            const i32x8 af = __builtin_shufflevector(a0, a1, 0, 1, 2, 3, 4, 5, 6, 7);
#pragma unroll
            for (int nj = 0; nj < 4; ++nj)
                acc[mi][nj] = __builtin_amdgcn_mfma_scale_f32_16x16x128_f8f6f4(
                    af, bf[nj], acc[mi][nj], 0, 0,        // cbsz=fp8, blgp=fp8
                    0, SCALE_ONE, 0, SCALE_ONE);          // opsel/scale A, opsel/scale B
        }
        __builtin_amdgcn_s_setprio(0);
        asm volatile("s_waitcnt lgkmcnt(0)" ::: "memory");  // LDS reads done
        __builtin_amdgcn_s_barrier();                       // buf[cur] free for STAGE(t+2)
    }
#undef STAGE

    // ---- epilogue: scale, fp16-round, LDS-staged coalesced f32 stores ----
    // C/D layout: col = lane&15, row = (lane>>4)*4 + reg
    float scv[4];
#pragma unroll
    for (int nj = 0; nj < 4; ++nj) scv[nj] = scale_b[n0 + wc * 64 + nj * 16 + lr];

    float* sC = (float*)smem;                 // 64 rows x stride 260 f32 = 66560 B
#pragma unroll
    for (int c = 0; c < 4; ++c) {             // chunk = 64 tile-rows
        __syncthreads();                      // sC free (K-loop done / prev chunk stored)
        if (wr == (c >> 1)) {
            const int mib = (c & 1) * 4;
#pragma unroll
            for (int mi2 = 0; mi2 < 4; ++mi2) {
#pragma unroll
                for (int nj = 0; nj < 4; ++nj) {
#pragma unroll
                    for (int r = 0; r < 4; ++r) {
                        const int rl = mi2 * 16 + lg * 4 + r;          // 0..63
                        const int cl = wc * 64 + nj * 16 + lr;         // 0..255
                        const float v = acc[mib + mi2][nj][r] * scv[nj];
                        sC[rl * 260 + cl] = (float)(_Float16)v;
                    }
                }
            }
        }
        __syncthreads();
        // 512 threads store 512 x 128B lines (64 rows x 1KB), fully coalesced
        const int row = tid >> 3, lin = tid & 7;
        const float* srcp = sC + row * 260 + lin * 32;
        float* dstp = out + (size_t)(m0 + c * 64 + row) * N_DIM + n0 + lin * 32;
#pragma unroll
        for (int q = 0; q < 8; ++q)
            ((f32x4*)dstp)[q] = ((const f32x4*)srcp)[q];
    }
}

// ---------------- fallback: round-6 fused kernel (passing, 350 us) ----------------
__global__ __launch_bounds__(256) void gemm_fused_kernel(const float* __restrict__ A,
                                                         const float* __restrict__ W,
                                                         const float* __restrict__ scale_b,
                                                         float* __restrict__ out) {
    __shared__ __attribute__((aligned(16))) unsigned char sA[128 * 64];
    __shared__ __attribute__((aligned(16))) unsigned char sB[64 * 128];

    const int tid = threadIdx.x;
    const int l = tid & 63;
    const int wid = tid >> 6;
    const int lr = l & 15;
    const int lg = l >> 4;
    const int wr = wid >> 1;
    const int wc = wid & 1;
    const int n0 = blockIdx.x * 128;
    const int m0 = blockIdx.y * 128;

    f32x4 acc[4][4];
#pragma unroll
    for (int i = 0; i < 4; ++i)
#pragma unroll
        for (int j = 0; j < 4; ++j) acc[i][j] = (f32x4)0.0f;

    const int a_g = tid & 7;
    const int a_rb = tid >> 3;
    const int aswz = lr & 6;

    for (int kt = 0; kt < K_DIM / 64; ++kt) {
        const int k0 = kt * 64;
#pragma unroll
        for (int o = 0; o < 4; ++o) {
            const int row = o * 32 + a_rb;
            const float* ap = A + (size_t)(m0 + row) * K_DIM + k0 + a_g * 8;
            const f32x4 v0 = *(const f32x4*)ap;
            const f32x4 v1 = *(const f32x4*)(ap + 4);
            u32x2 r;
            r.x = cvt4(v0[0], v0[1], v0[2], v0[3]);
            r.y = cvt4(v1[0], v1[1], v1[2], v1[3]);
            *(u32x2*)(sA + row * 64 + ((a_g ^ (row & 6)) * 8)) = r;
        }
#pragma unroll
        for (int o = 0; o < 4; ++o) {
            const int e = o * 256 + tid;
            const int g = e >> 7;
            const int n = e & 127;
            const float* wp = W + (size_t)(k0 + g * 8) * N_DIM + n0 + n;
            float f[8];
#pragma unroll
            for (int j = 0; j < 8; ++j) f[j] = wp[(size_t)j * N_DIM];
            u32x2 r;
            r.x = cvt4(f[0], f[1], f[2], f[3]);
            r.y = cvt4(f[4], f[5], f[6], f[7]);
            *(u32x2*)(sB + g * 1024 + n * 8) = r;
        }
        __syncthreads();

#pragma unroll
        for (int kk = 0; kk < 2; ++kk) {
            long long af[4], bfr[4];
            const int gread = kk * 4 + lg;
#pragma unroll
            for (int mi = 0; mi < 4; ++mi) {
                const int m = wr * 64 + mi * 16 + lr;
                af[mi] = *(const long long*)(sA + m * 64 + ((gread ^ aswz) * 8));
            }
#pragma unroll
            for (int nj = 0; nj < 4; ++nj) {
                const int n = wc * 64 + nj * 16 + lr;
                bfr[nj] = *(const long long*)(sB + gread * 1024 + n * 8);
            }
#pragma unroll
            for (int mi = 0; mi < 4; ++mi)
#pragma unroll
                for (int nj = 0; nj < 4; ++nj)
                    acc[mi][nj] = __builtin_amdgcn_mfma_f32_16x16x32_fp8_fp8(
                        af[mi], bfr[nj], acc[mi][nj], 0, 0, 0);
        }
        __syncthreads();
    }

#pragma unroll
    for (int nj = 0; nj < 4; ++nj) {
        const int col = n0 + wc * 64 + nj * 16 + lr;
        const float sc = scale_b[col];
#pragma unroll
        for (int mi = 0; mi < 4; ++mi) {
            const int row = m0 + wr * 64 + mi * 16 + lg * 4;
#pragma unroll
            for (int r = 0; r < 4; ++r) {
                const float v = acc[mi][nj][r] * sc;
                out[(size_t)(row + r) * N_DIM + col] = (float)(_Float16)v;
            }
        }
    }
}

extern "C" void kernel_launch(void* const* d_in, const int* in_sizes, int n_in,
                              void* d_out, int out_size, void* d_ws, size_t ws_size,
                              hipStream_t stream) {
    (void)out_size;
    const void* pA = d_in[0];
    const void* pW = (n_in > 1) ? d_in[1] : d_in[0];
    const void* pS = (n_in > 2) ? d_in[2] : d_in[0];
    for (int i = 0; i < n_in && i < 3; ++i) {
        if (in_sizes[i] == M_DIM * K_DIM) pA = d_in[i];
        else if (in_sizes[i] == K_DIM * N_DIM) pW = d_in[i];
        else if (in_sizes[i] == N_DIM) pS = d_in[i];
    }
    const float* A = (const float*)pA;
    const float* W = (const float*)pW;
    const float* sb = (const float*)pS;
    float* out = (float*)d_out;

    if (ws_size >= WS_NEEDED && d_ws != nullptr) {
        unsigned char* A8 = (unsigned char*)d_ws;
        unsigned char* W8 = A8 + (size_t)M_DIM * K_DIM;
        quant_a_kernel<<<2048, 256, 0, stream>>>(A, A8);
        quant_w_kernel<<<256, 256, 0, stream>>>(W, W8);
        gemm_fp8_kernel<<<(M_DIM / BM) * (N_DIM / BN), 512, 0, stream>>>(A8, W8, sb, out);
    } else {
        gemm_fused_kernel<<<dim3(N_DIM / 128, M_DIM / 128), 256, 0, stream>>>(A, W, sb, out);
    }
}

// Round 12
// 237.640 us; speedup vs baseline: 1.0342x; 1.0193x over previous
//
#include <hip/hip_runtime.h>

#define AS1 __attribute__((address_space(1)))
#define AS3 __attribute__((address_space(3)))

typedef float __attribute__((ext_vector_type(4))) f32x4;
typedef unsigned int __attribute__((ext_vector_type(2))) u32x2;
typedef int __attribute__((ext_vector_type(4))) i32x4;
typedef int __attribute__((ext_vector_type(8))) i32x8;

#define M_DIM 65536
#define N_DIM 1024
#define K_DIM 1024

#define BM 256
#define BN 256
#define BK 128

#define WS_NEEDED ((size_t)M_DIM * K_DIM + (size_t)K_DIM * N_DIM)  // A8 64MB + W8 1MB
#define SCALE_ONE 0x7F7F7F7F  // e8m0 127 = 2^0 in every byte -> scale 1.0

// pack 4 floats -> 4 fp8 e4m3 bytes (RNE, OCP on gfx950)
__device__ inline unsigned int cvt4(float f0, float f1, float f2, float f3) {
    int r = __builtin_amdgcn_cvt_pk_fp8_f32(f0, f1, 0, false);
    r = __builtin_amdgcn_cvt_pk_fp8_f32(f2, f3, r, true);
    return (unsigned int)r;
}

// ---------------- pass 1a: A f32 -> fp8 row-major ----------------
__global__ __launch_bounds__(256) void quant_a_kernel(const float* __restrict__ in,
                                                      unsigned char* __restrict__ out) {
    const int total8 = (M_DIM * K_DIM) / 8;
    const int stride = 2048 * 256;
    for (int i = blockIdx.x * 256 + threadIdx.x; i < total8; i += stride) {
        const float* p = in + (size_t)i * 8;
        const f32x4 v0 = *(const f32x4*)p;
        const f32x4 v1 = *(const f32x4*)(p + 4);
        u32x2 r;
        r.x = cvt4(v0[0], v0[1], v0[2], v0[3]);
        r.y = cvt4(v1[0], v1[1], v1[2], v1[3]);
        ((u32x2*)out)[i] = r;
    }
}

// ---------------- pass 1b: W f32 -> fp8 packed [K/16][N][16] ----------------
__global__ __launch_bounds__(256) void quant_w_kernel(const float* __restrict__ w,
                                                      unsigned char* __restrict__ out) {
    const int idx = blockIdx.x * 256 + threadIdx.x;  // 0..65535
    const int t = idx >> 10, n = idx & 1023;
    const float* wp = w + (size_t)(t * 16) * N_DIM + n;
    unsigned int r[4];
#pragma unroll
    for (int q = 0; q < 4; ++q) {
        float f0 = wp[(size_t)(q * 4 + 0) * N_DIM];
        float f1 = wp[(size_t)(q * 4 + 1) * N_DIM];
        float f2 = wp[(size_t)(q * 4 + 2) * N_DIM];
        float f3 = wp[(size_t)(q * 4 + 3) * N_DIM];
        r[q] = cvt4(f0, f1, f2, f3);
    }
    i32x4 v; v.x = (int)r[0]; v.y = (int)r[1]; v.z = (int)r[2]; v.w = (int)r[3];
    ((i32x4*)out)[idx] = v;
}

// ---------------- pass 2: MX-fp8 GEMM, 256x256, 4-phase schedule ----------------
// Per K-tile: [vmcnt(0); barrier]  then 4 phases:
//   {barrier(p>0); ds_read subtile; issue 2 next-tile gload_lds; setprio(1); 8 MFMA; setprio(0)}
// Next-tile loads stay in flight across phase barriers; waited at next tile-top
// (issued a full tile of compute earlier -> free). lgkmcnt(0) at tile end.
__global__ __launch_bounds__(512) void gemm_fp8_kernel(const unsigned char* __restrict__ A8,
                                                       const unsigned char* __restrict__ B8,
                                                       const float* __restrict__ scale_b,
                                                       float* __restrict__ out) {
    __shared__ __attribute__((aligned(16))) unsigned char smem[131072];  // A:2x32K, B:2x32K

    const int tid = threadIdx.x;
    const int l = tid & 63;
    const int wid = tid >> 6;        // 0..7
    const int lr = l & 15;
    const int lg = l >> 4;           // k-quarter
    const int wr = wid >> 2;         // wave row 0..1 (128 rows each)
    const int wc = wid & 3;          // wave col 0..3 (64 cols each)

    // XCD swizzle: 1024 blocks, XCD = b&7; each XCD owns 32 consecutive m-panels.
    const int b = blockIdx.x;
    const int local = b >> 3;
    const int m_idx = (b & 7) * 32 + (local >> 2);
    const int n_idx = local & 3;
    const int m0 = m_idx * BM;
    const int n0 = n_idx * BN;

    f32x4 acc[8][4];
#pragma unroll
    for (int i = 0; i < 8; ++i)
#pragma unroll
        for (int j = 0; j < 4; ++j) acc[i][j] = (f32x4)0.0f;

    // A staging: chunk = 8 rows x 128B; lane l -> row l>>3, dest 16B unit l&7
    const int a_rl = l >> 3;
    const int a_u = l & 7;

    // One substage = 1 A-chunk + 1 B-chunk (2 gload_lds per thread).
#define SUBSTAGE(T, C, SAB, SBB)                                                        \
    do {                                                                                \
        const int k0s = (T) * BK;                                                       \
        {                                                                               \
            const int i = wid * 4 + (C);                                                \
            const int row = i * 8 + a_rl;                                               \
            const unsigned char* src =                                                  \
                A8 + (size_t)(m0 + row) * K_DIM + k0s + ((a_u ^ (row & 7)) * 16);       \
            __builtin_amdgcn_global_load_lds((const AS1 void*)src,                      \
                                             (AS3 void*)((SAB) + i * 1024), 16, 0, 0);  \
        }                                                                               \
        {                                                                               \
            const int idx = wid * 4 + (C);                                              \
            const int tt = idx >> 2, q = idx & 3;                                       \
            const unsigned char* src =                                                  \
                B8 + ((size_t)((T) * 8 + tt) * N_DIM + n0 + q * 64) * 16 + l * 16;      \
            __builtin_amdgcn_global_load_lds((const AS1 void*)src,                      \
                                             (AS3 void*)((SBB) + tt * 4096 + q * 1024), 16, 0, 0); \
        }                                                                               \
    } while (0)

    // prologue: stage tile 0 fully
#pragma unroll
    for (int c = 0; c < 4; ++c) SUBSTAGE(0, c, smem, smem + 65536);

#pragma unroll
    for (int t = 0; t < K_DIM / BK; ++t) {
        const int cur = t & 1;
        const unsigned char* sAc = smem + cur * 32768;
        const unsigned char* sBc = smem + 65536 + cur * 32768;
        unsigned char* sAn = smem + (cur ^ 1) * 32768;
        unsigned char* sBn = smem + 65536 + (cur ^ 1) * 32768;

        asm volatile("s_waitcnt vmcnt(0)" ::: "memory");  // tile t landed (issued ~1 tile ago)
        __builtin_amdgcn_s_barrier();                     // buf[cur] published

        i32x8 bf[4];
#pragma unroll
        for (int p = 0; p < 4; ++p) {
            if (p) __builtin_amdgcn_s_barrier();          // phase gate (no drain)
            if (p == 0) {
#pragma unroll
                for (int nj = 0; nj < 4; ++nj) {
                    const int n = wc * 64 + nj * 16 + lr;
                    const i32x4 b0 = *(const i32x4*)(sBc + (lg * 2 + 0) * 4096 + n * 16);
                    const i32x4 b1 = *(const i32x4*)(sBc + (lg * 2 + 1) * 4096 + n * 16);
                    bf[nj] = __builtin_shufflevector(b0, b1, 0, 1, 2, 3, 4, 5, 6, 7);
                }
            }
            // af for mi = 2p, 2p+1
            i32x8 af[2];
#pragma unroll
            for (int s = 0; s < 2; ++s) {
                const int r = wr * 128 + (2 * p + s) * 16 + lr;
                const i32x4 a0 = *(const i32x4*)(sAc + r * 128 + (((2 * lg + 0) ^ (r & 7)) * 16));
                const i32x4 a1 = *(const i32x4*)(sAc + r * 128 + (((2 * lg + 1) ^ (r & 7)) * 16));
                af[s] = __builtin_shufflevector(a0, a1, 0, 1, 2, 3, 4, 5, 6, 7);
            }
            if (t < K_DIM / BK - 1) SUBSTAGE(t + 1, p, sAn, sBn);  // 2 loads, fly across barriers

            __builtin_amdgcn_s_setprio(1);
#pragma unroll
            for (int s = 0; s < 2; ++s)
#pragma unroll
                for (int nj = 0; nj < 4; ++nj)
                    acc[2 * p + s][nj] = __builtin_amdgcn_mfma_scale_f32_16x16x128_f8f6f4(
                        af[s], bf[nj], acc[2 * p + s][nj], 0, 0,
                        0, SCALE_ONE, 0, SCALE_ONE);
            __builtin_amdgcn_s_setprio(0);
        }
        asm volatile("s_waitcnt lgkmcnt(0)" ::: "memory");  // buf[cur] reads retired
    }
#undef SUBSTAGE

    // ---- epilogue: scale, fp16-round, LDS-staged coalesced f32 stores ----
    // C/D layout: col = lane&15, row = (lane>>4)*4 + reg
    float scv[4];
#pragma unroll
    for (int nj = 0; nj < 4; ++nj) scv[nj] = scale_b[n0 + wc * 64 + nj * 16 + lr];

    float* sC = (float*)smem;                 // 64 rows x stride 260 f32
#pragma unroll
    for (int c = 0; c < 4; ++c) {             // chunk = 64 tile-rows
        __syncthreads();
        if (wr == (c >> 1)) {
            const int mib = (c & 1) * 4;
#pragma unroll
            for (int mi2 = 0; mi2 < 4; ++mi2) {
#pragma unroll
                for (int nj = 0; nj < 4; ++nj) {
#pragma unroll
                    for (int r = 0; r < 4; ++r) {
                        const int rl = mi2 * 16 + lg * 4 + r;
                        const int cl = wc * 64 + nj * 16 + lr;
                        const float v = acc[mib + mi2][nj][r] * scv[nj];
                        sC[rl * 260 + cl] = (float)(_Float16)v;
                    }
                }
            }
        }
        __syncthreads();
        const int row = tid >> 3, lin = tid & 7;
        const float* srcp = sC + row * 260 + lin * 32;
        float* dstp = out + (size_t)(m0 + c * 64 + row) * N_DIM + n0 + lin * 32;
#pragma unroll
        for (int q = 0; q < 8; ++q)
            ((f32x4*)dstp)[q] = ((const f32x4*)srcp)[q];
    }
}

// ---------------- fallback: round-6 fused kernel (passing, 350 us) ----------------
__global__ __launch_bounds__(256) void gemm_fused_kernel(const float* __restrict__ A,
                                                         const float* __restrict__ W,
                                                         const float* __restrict__ scale_b,
                                                         float* __restrict__ out) {
    __shared__ __attribute__((aligned(16))) unsigned char sA[128 * 64];
    __shared__ __attribute__((aligned(16))) unsigned char sB[64 * 128];

    const int tid = threadIdx.x;
    const int l = tid & 63;
    const int wid = tid >> 6;
    const int lr = l & 15;
    const int lg = l >> 4;
    const int wr = wid >> 1;
    const int wc = wid & 1;
    const int n0 = blockIdx.x * 128;
    const int m0 = blockIdx.y * 128;

    f32x4 acc[4][4];
#pragma unroll
    for (int i = 0; i < 4; ++i)
#pragma unroll
        for (int j = 0; j < 4; ++j) acc[i][j] = (f32x4)0.0f;

    const int a_g = tid & 7;
    const int a_rb = tid >> 3;
    const int aswz = lr & 6;

    for (int kt = 0; kt < K_DIM / 64; ++kt) {
        const int k0 = kt * 64;
#pragma unroll
        for (int o = 0; o < 4; ++o) {
            const int row = o * 32 + a_rb;
            const float* ap = A + (size_t)(m0 + row) * K_DIM + k0 + a_g * 8;
            const f32x4 v0 = *(const f32x4*)ap;
            const f32x4 v1 = *(const f32x4*)(ap + 4);
            u32x2 r;
            r.x = cvt4(v0[0], v0[1], v0[2], v0[3]);
            r.y = cvt4(v1[0], v1[1], v1[2], v1[3]);
            *(u32x2*)(sA + row * 64 + ((a_g ^ (row & 6)) * 8)) = r;
        }
#pragma unroll
        for (int o = 0; o < 4; ++o) {
            const int e = o * 256 + tid;
            const int g = e >> 7;
            const int n = e & 127;
            const float* wp = W + (size_t)(k0 + g * 8) * N_DIM + n0 + n;
            float f[8];
#pragma unroll
            for (int j = 0; j < 8; ++j) f[j] = wp[(size_t)j * N_DIM];
            u32x2 r;
            r.x = cvt4(f[0], f[1], f[2], f[3]);
            r.y = cvt4(f[4], f[5], f[6], f[7]);
            *(u32x2*)(sB + g * 1024 + n * 8) = r;
        }
        __syncthreads();

#pragma unroll
        for (int kk = 0; kk < 2; ++kk) {
            long long af[4], bfr[4];
            const int gread = kk * 4 + lg;
#pragma unroll
            for (int mi = 0; mi < 4; ++mi) {
                const int m = wr * 64 + mi * 16 + lr;
                af[mi] = *(const long long*)(sA + m * 64 + ((gread ^ aswz) * 8));
            }
#pragma unroll
            for (int nj = 0; nj < 4; ++nj) {
                const int n = wc * 64 + nj * 16 + lr;
                bfr[nj] = *(const long long*)(sB + gread * 1024 + n * 8);
            }
#pragma unroll
            for (int mi = 0; mi < 4; ++mi)
#pragma unroll
                for (int nj = 0; nj < 4; ++nj)
                    acc[mi][nj] = __builtin_amdgcn_mfma_f32_16x16x32_fp8_fp8(
                        af[mi], bfr[nj], acc[mi][nj], 0, 0, 0);
        }
        __syncthreads();
    }

#pragma unroll
    for (int nj = 0; nj < 4; ++nj) {
        const int col = n0 + wc * 64 + nj * 16 + lr;
        const float sc = scale_b[col];
#pragma unroll
        for (int mi = 0; mi < 4; ++mi) {
            const int row = m0 + wr * 64 + mi * 16 + lg * 4;
#pragma unroll
            for (int r = 0; r < 4; ++r) {
                const float v = acc[mi][nj][r] * sc;
                out[(size_t)(row + r) * N_DIM + col] = (float)(_Float16)v;
            }
        }
    }
}

extern "C" void kernel_launch(void* const* d_in, const int* in_sizes, int n_in,
                              void* d_out, int out_size, void* d_ws, size_t ws_size,
                              hipStream_t stream) {
    (void)out_size;
    const void* pA = d_in[0];
    const void* pW = (n_in > 1) ? d_in[1] : d_in[0];
    const void* pS = (n_in > 2) ? d_in[2] : d_in[0];
    for (int i = 0; i < n_in && i < 3; ++i) {
        if (in_sizes[i] == M_DIM * K_DIM) pA = d_in[i];
        else if (in_sizes[i] == K_DIM * N_DIM) pW = d_in[i];
        else if (in_sizes[i] == N_DIM) pS = d_in[i];
    }
    const float* A = (const float*)pA;
    const float* W = (const float*)pW;
    const float* sb = (const float*)pS;
    float* out = (float*)d_out;

    if (ws_size >= WS_NEEDED && d_ws != nullptr) {
        unsigned char* A8 = (unsigned char*)d_ws;
        unsigned char* W8 = A8 + (size_t)M_DIM * K_DIM;
        quant_a_kernel<<<2048, 256, 0, stream>>>(A, A8);
        quant_w_kernel<<<256, 256, 0, stream>>>(W, W8);
        gemm_fp8_kernel<<<(M_DIM / BM) * (N_DIM / BN), 512, 0, stream>>>(A8, W8, sb, out);
    } else {
        gemm_fused_kernel<<<dim3(N_DIM / 128, M_DIM / 128), 256, 0, stream>>>(A, W, sb, out);
    }
}

// Round 13
// 215.744 us; speedup vs baseline: 1.1392x; 1.1015x over previous
//
#include <hip/hip_runtime.h>

#define AS1 __attribute__((address_space(1)))
#define AS3 __attribute__((address_space(3)))

typedef float __attribute__((ext_vector_type(4))) f32x4;
typedef unsigned int __attribute__((ext_vector_type(2))) u32x2;
typedef int __attribute__((ext_vector_type(4))) i32x4;
typedef int __attribute__((ext_vector_type(8))) i32x8;

#define M_DIM 65536
#define N_DIM 1024
#define K_DIM 1024

#define BM 128
#define BN 128
#define BK 128

#define WS_NEEDED ((size_t)M_DIM * K_DIM + (size_t)K_DIM * N_DIM)  // A8 64MB + W8 1MB
#define SCALE_ONE 0x7F7F7F7F  // e8m0 127 = 2^0 in every byte -> scale 1.0

// pack 4 floats -> 4 fp8 e4m3 bytes (RNE, OCP on gfx950)
__device__ inline unsigned int cvt4(float f0, float f1, float f2, float f3) {
    int r = __builtin_amdgcn_cvt_pk_fp8_f32(f0, f1, 0, false);
    r = __builtin_amdgcn_cvt_pk_fp8_f32(f2, f3, r, true);
    return (unsigned int)r;
}

// ---------------- pass 1a: A f32 -> fp8 row-major ----------------
__global__ __launch_bounds__(256) void quant_a_kernel(const float* __restrict__ in,
                                                      unsigned char* __restrict__ out) {
    const int total8 = (M_DIM * K_DIM) / 8;
    const int stride = 2048 * 256;
    for (int i = blockIdx.x * 256 + threadIdx.x; i < total8; i += stride) {
        const float* p = in + (size_t)i * 8;
        const f32x4 v0 = *(const f32x4*)p;
        const f32x4 v1 = *(const f32x4*)(p + 4);
        u32x2 r;
        r.x = cvt4(v0[0], v0[1], v0[2], v0[3]);
        r.y = cvt4(v1[0], v1[1], v1[2], v1[3]);
        ((u32x2*)out)[i] = r;
    }
}

// ---------------- pass 1b: W f32 -> fp8 packed [K/16][N][16] ----------------
// out[(t*N + n)*16 + s] = fp8(W[t*16 + s][n])
__global__ __launch_bounds__(256) void quant_w_kernel(const float* __restrict__ w,
                                                      unsigned char* __restrict__ out) {
    const int idx = blockIdx.x * 256 + threadIdx.x;  // 0..65535
    const int t = idx >> 10, n = idx & 1023;
    const float* wp = w + (size_t)(t * 16) * N_DIM + n;
    unsigned int r[4];
#pragma unroll
    for (int q = 0; q < 4; ++q) {
        float f0 = wp[(size_t)(q * 4 + 0) * N_DIM];
        float f1 = wp[(size_t)(q * 4 + 1) * N_DIM];
        float f2 = wp[(size_t)(q * 4 + 2) * N_DIM];
        float f3 = wp[(size_t)(q * 4 + 3) * N_DIM];
        r[q] = cvt4(f0, f1, f2, f3);
    }
    i32x4 v; v.x = (int)r[0]; v.y = (int)r[1]; v.z = (int)r[2]; v.w = (int)r[3];
    ((i32x4*)out)[idx] = v;
}

// ---------------- pass 2: MX-fp8 GEMM, 128x128, A via LDS, B direct from L2 ----------------
// Round-8 structure (proven best: ~150us gemm) minus B staging:
//   per K-tile { stage A (4 gload_lds/thread); __syncthreads; bf from GLOBAL (L2-resident
//   1MB W8); af from LDS; 16 MFMA/wave; __syncthreads }
// LDS = 16 KB -> up to 10 blocks/CU; half the drain mass per barrier; no B ds_reads.
__global__ __launch_bounds__(256) void gemm_fp8_kernel(const unsigned char* __restrict__ A8,
                                                       const unsigned char* __restrict__ B8,
                                                       const float* __restrict__ scale_b,
                                                       float* __restrict__ out) {
    __shared__ __attribute__((aligned(16))) unsigned char sA[BM * BK];  // 16 KB

    const int tid = threadIdx.x;
    const int l = tid & 63;
    const int wid = tid >> 6;        // 0..3
    const int lr = l & 15;
    const int lg = l >> 4;           // k-quarter
    const int wr = wid >> 1;         // wave row 0..1 (64 rows each)
    const int wc = wid & 1;          // wave col 0..1 (64 cols each)

    // XCD swizzle: 4096 blocks, XCD = b&7. Each XCD owns 64 consecutive m-panels;
    // within a panel the 8 n-tiles run back-to-back (A8-panel 128KB L2-resident).
    const int b = blockIdx.x;
    const int local = b >> 3;                         // 0..511
    const int m_idx = (b & 7) * 64 + (local >> 3);    // 0..511
    const int n_idx = local & 7;                      // 0..7
    const int m0 = m_idx * BM;
    const int n0 = n_idx * BN;

    f32x4 acc[4][4];
#pragma unroll
    for (int i = 0; i < 4; ++i)
#pragma unroll
        for (int j = 0; j < 4; ++j) acc[i][j] = (f32x4)0.0f;

    // A staging: chunk = 8 rows x 128B; lane l -> row l>>3, dest 16B unit l&7
    const int a_rl = l >> 3;
    const int a_u = l & 7;

    for (int kt = 0; kt < K_DIM / BK; ++kt) {
        const int k0 = kt * BK;
        // ---- stage A: 16 chunks of 1KB; this wave does 4 (4 gload_lds/thread) ----
#pragma unroll
        for (int c = 0; c < 4; ++c) {
            const int i = wid * 4 + c;
            const int row = i * 8 + a_rl;             // 0..127
            const unsigned char* src =
                A8 + (size_t)(m0 + row) * K_DIM + k0 + ((a_u ^ (row & 7)) * 16);
            __builtin_amdgcn_global_load_lds((const AS1 void*)src,
                                             (AS3 void*)(sA + i * 1024), 16, 0, 0);
        }
        __syncthreads();  // drains vmcnt (A loads) — half the mass of round 8

        // ---- bf direct from global (L2-resident W8), af from LDS ----
        i32x8 bf[4];
#pragma unroll
        for (int nj = 0; nj < 4; ++nj) {
            const int n = n0 + wc * 64 + nj * 16 + lr;
            const size_t base = ((size_t)(kt * 8 + lg * 2) * N_DIM + n) * 16;
            const i32x4 b0 = *(const i32x4*)(B8 + base);
            const i32x4 b1 = *(const i32x4*)(B8 + base + (size_t)N_DIM * 16);
            bf[nj] = __builtin_shufflevector(b0, b1, 0, 1, 2, 3, 4, 5, 6, 7);
        }
#pragma unroll
        for (int mi = 0; mi < 4; ++mi) {
            const int r = wr * 64 + mi * 16 + lr;
            const i32x4 a0 = *(const i32x4*)(sA + r * 128 + (((2 * lg + 0) ^ (r & 7)) * 16));
            const i32x4 a1 = *(const i32x4*)(sA + r * 128 + (((2 * lg + 1) ^ (r & 7)) * 16));
            const i32x8 af = __builtin_shufflevector(a0, a1, 0, 1, 2, 3, 4, 5, 6, 7);
#pragma unroll
            for (int nj = 0; nj < 4; ++nj)
                acc[mi][nj] = __builtin_amdgcn_mfma_scale_f32_16x16x128_f8f6f4(
                    af, bf[nj], acc[mi][nj], 0, 0,        // cbsz=fp8, blgp=fp8
                    0, SCALE_ONE, 0, SCALE_ONE);
        }
        __syncthreads();  // LDS reads retired before next-tile overwrite
    }

    // ---- epilogue: scale, round through fp16, store f32 (merged fine at 128²) ----
    // C/D layout: col = lane&15, row = (lane>>4)*4 + reg
#pragma unroll
    for (int nj = 0; nj < 4; ++nj) {
        const int col = n0 + wc * 64 + nj * 16 + lr;
        const float sc = scale_b[col];
#pragma unroll
        for (int mi = 0; mi < 4; ++mi) {
            const int row = m0 + wr * 64 + mi * 16 + lg * 4;
#pragma unroll
            for (int r = 0; r < 4; ++r) {
                const float v = acc[mi][nj][r] * sc;
                out[(size_t)(row + r) * N_DIM + col] = (float)(_Float16)v;
            }
        }
    }
}

// ---------------- fallback: round-6 fused kernel (passing, 350 us) ----------------
__global__ __launch_bounds__(256) void gemm_fused_kernel(const float* __restrict__ A,
                                                         const float* __restrict__ W,
                                                         const float* __restrict__ scale_b,
                                                         float* __restrict__ out) {
    __shared__ __attribute__((aligned(16))) unsigned char sA[128 * 64];
    __shared__ __attribute__((aligned(16))) unsigned char sB[64 * 128];

    const int tid = threadIdx.x;
    const int l = tid & 63;
    const int wid = tid >> 6;
    const int lr = l & 15;
    const int lg = l >> 4;
    const int wr = wid >> 1;
    const int wc = wid & 1;
    const int n0 = blockIdx.x * 128;
    const int m0 = blockIdx.y * 128;

    f32x4 acc[4][4];
#pragma unroll
    for (int i = 0; i < 4; ++i)
#pragma unroll
        for (int j = 0; j < 4; ++j) acc[i][j] = (f32x4)0.0f;

    const int a_g = tid & 7;
    const int a_rb = tid >> 3;
    const int aswz = lr & 6;

    for (int kt = 0; kt < K_DIM / 64; ++kt) {
        const int k0 = kt * 64;
#pragma unroll
        for (int o = 0; o < 4; ++o) {
            const int row = o * 32 + a_rb;
            const float* ap = A + (size_t)(m0 + row) * K_DIM + k0 + a_g * 8;
            const f32x4 v0 = *(const f32x4*)ap;
            const f32x4 v1 = *(const f32x4*)(ap + 4);
            u32x2 r;
            r.x = cvt4(v0[0], v0[1], v0[2], v0[3]);
            r.y = cvt4(v1[0], v1[1], v1[2], v1[3]);
            *(u32x2*)(sA + row * 64 + ((a_g ^ (row & 6)) * 8)) = r;
        }
#pragma unroll
        for (int o = 0; o < 4; ++o) {
            const int e = o * 256 + tid;
            const int g = e >> 7;
            const int n = e & 127;
            const float* wp = W + (size_t)(k0 + g * 8) * N_DIM + n0 + n;
            float f[8];
#pragma unroll
            for (int j = 0; j < 8; ++j) f[j] = wp[(size_t)j * N_DIM];
            u32x2 r;
            r.x = cvt4(f[0], f[1], f[2], f[3]);
            r.y = cvt4(f[4], f[5], f[6], f[7]);
            *(u32x2*)(sB + g * 1024 + n * 8) = r;
        }
        __syncthreads();

#pragma unroll
        for (int kk = 0; kk < 2; ++kk) {
            long long af[4], bfr[4];
            const int gread = kk * 4 + lg;
#pragma unroll
            for (int mi = 0; mi < 4; ++mi) {
                const int m = wr * 64 + mi * 16 + lr;
                af[mi] = *(const long long*)(sA + m * 64 + ((gread ^ aswz) * 8));
            }
#pragma unroll
            for (int nj = 0; nj < 4; ++nj) {
                const int n = wc * 64 + nj * 16 + lr;
                bfr[nj] = *(const long long*)(sB + gread * 1024 + n * 8);
            }
#pragma unroll
            for (int mi = 0; mi < 4; ++mi)
#pragma unroll
                for (int nj = 0; nj < 4; ++nj)
                    acc[mi][nj] = __builtin_amdgcn_mfma_f32_16x16x32_fp8_fp8(
                        af[mi], bfr[nj], acc[mi][nj], 0, 0, 0);
        }
        __syncthreads();
    }

#pragma unroll
    for (int nj = 0; nj < 4; ++nj) {
        const int col = n0 + wc * 64 + nj * 16 + lr;
        const float sc = scale_b[col];
#pragma unroll
        for (int mi = 0; mi < 4; ++mi) {
            const int row = m0 + wr * 64 + mi * 16 + lg * 4;
#pragma unroll
            for (int r = 0; r < 4; ++r) {
                const float v = acc[mi][nj][r] * sc;
                out[(size_t)(row + r) * N_DIM + col] = (float)(_Float16)v;
            }
        }
    }
}

extern "C" void kernel_launch(void* const* d_in, const int* in_sizes, int n_in,
                              void* d_out, int out_size, void* d_ws, size_t ws_size,
                              hipStream_t stream) {
    (void)out_size;
    const void* pA = d_in[0];
    const void* pW = (n_in > 1) ? d_in[1] : d_in[0];
    const void* pS = (n_in > 2) ? d_in[2] : d_in[0];
    for (int i = 0; i < n_in && i < 3; ++i) {
        if (in_sizes[i] == M_DIM * K_DIM) pA = d_in[i];
        else if (in_sizes[i] == K_DIM * N_DIM) pW = d_in[i];
        else if (in_sizes[i] == N_DIM) pS = d_in[i];
    }
    const float* A = (const float*)pA;
    const float* W = (const float*)pW;
    const float* sb = (const float*)pS;
    float* out = (float*)d_out;

    if (ws_size >= WS_NEEDED && d_ws != nullptr) {
        unsigned char* A8 = (unsigned char*)d_ws;
        unsigned char* W8 = A8 + (size_t)M_DIM * K_DIM;
        quant_a_kernel<<<2048, 256, 0, stream>>>(A, A8);
        quant_w_kernel<<<256, 256, 0, stream>>>(W, W8);
        gemm_fp8_kernel<<<(M_DIM / BM) * (N_DIM / BN), 256, 0, stream>>>(A8, W8, sb, out);
    } else {
        gemm_fused_kernel<<<dim3(N_DIM / 128, M_DIM / 128), 256, 0, stream>>>(A, W, sb, out);
    }
}

// Round 14
// 178.336 us; speedup vs baseline: 1.3781x; 1.2098x over previous
//
#include <hip/hip_runtime.h>

typedef float __attribute__((ext_vector_type(4))) f32x4;
typedef unsigned int __attribute__((ext_vector_type(2))) u32x2;
typedef int __attribute__((ext_vector_type(4))) i32x4;
typedef int __attribute__((ext_vector_type(8))) i32x8;

#define M_DIM 65536
#define N_DIM 1024
#define K_DIM 1024

#define BM 64            // rows per block; block covers full N via 8 chunks of 128

#define WS_NEEDED ((size_t)K_DIM * N_DIM)   // W8 only: 1 MB
#define SCALE_ONE 0x7F7F7F7F                // e8m0 127 = 2^0 -> scale 1.0

// pack 4 floats -> 4 fp8 e4m3 bytes (RNE, OCP on gfx950)
__device__ inline unsigned int cvt4(float f0, float f1, float f2, float f3) {
    int r = __builtin_amdgcn_cvt_pk_fp8_f32(f0, f1, 0, false);
    r = __builtin_amdgcn_cvt_pk_fp8_f32(f2, f3, r, true);
    return (unsigned int)r;
}

// ---------------- pass 1: W f32 -> fp8 packed [K/16][N][16] ----------------
// out[(t*N + n)*16 + s] = fp8(W[t*16 + s][n])
__global__ __launch_bounds__(256) void quant_w_kernel(const float* __restrict__ w,
                                                      unsigned char* __restrict__ out) {
    const int idx = blockIdx.x * 256 + threadIdx.x;  // 0..65535
    const int t = idx >> 10, n = idx & 1023;
    const float* wp = w + (size_t)(t * 16) * N_DIM + n;
    unsigned int r[4];
#pragma unroll
    for (int q = 0; q < 4; ++q) {
        float f0 = wp[(size_t)(q * 4 + 0) * N_DIM];
        float f1 = wp[(size_t)(q * 4 + 1) * N_DIM];
        float f2 = wp[(size_t)(q * 4 + 2) * N_DIM];
        float f3 = wp[(size_t)(q * 4 + 3) * N_DIM];
        r[q] = cvt4(f0, f1, f2, f3);
    }
    i32x4 v; v.x = (int)r[0]; v.y = (int)r[1]; v.z = (int)r[2]; v.w = (int)r[3];
    ((i32x4*)out)[idx] = v;
}

// ---------------- pass 2: fused quantize+GEMM, 64 rows x full N per block ----------------
// Stage: A f32 (64x1024, read ONCE from HBM) -> fp8 RNE -> LDS 64KB, XOR(row&7) 16B-unit
// swizzle. ONE __syncthreads. Then 8 chunks of 128 cols: af from LDS, bf direct from
// L2-resident W8, 16x16x128 MX-MFMA (scale=1.0), store chunk. No further barriers.
// 8 waves = 2 (row) x 4 (col); per chunk each wave owns 32 rows x 32 cols (2x2 frags).
__global__ __launch_bounds__(512) void gemm_fused2_kernel(const float* __restrict__ A,
                                                          const unsigned char* __restrict__ B8,
                                                          const float* __restrict__ scale_b,
                                                          float* __restrict__ out) {
    __shared__ __attribute__((aligned(16))) unsigned char sA[BM * K_DIM];  // 64 KB

    const int tid = threadIdx.x;
    const int l = tid & 63;
    const int wid = tid >> 6;        // 0..7
    const int lr = l & 15;
    const int lg = l >> 4;           // k-quarter
    const int wr2 = wid >> 2;        // 0..1: row half (32 rows)
    const int wc2 = wid & 3;         // 0..3: col quarter within chunk (32 cols)
    const int m0 = blockIdx.x * BM;

    // ---- stage + quantize A (once): 16384 f32x4 units, unit u = tid + j*512 ----
    // row = u>>8, kq = u&255 (f32x4 index), k = kq*4. Lane-consecutive u => coalesced.
    // LDS byte = row*1024 + ((k>>4)^(row&7))*16 + (k&15); b32 writes, 2-way banks (free).
#pragma unroll
    for (int j = 0; j < 32; ++j) {
        const int u = tid + j * 512;
        const int row = u >> 8;
        const int kq = u & 255;
        const f32x4 v = *(const f32x4*)(A + (size_t)(m0 + row) * K_DIM + kq * 4);
        const unsigned int w = cvt4(v[0], v[1], v[2], v[3]);
        const int k = kq * 4;
        *(unsigned int*)(sA + row * 1024 + (((k >> 4) ^ (row & 7)) << 4) + (k & 15)) = w;
    }
    __syncthreads();   // only barrier: sA is read-only afterwards

    for (int ch = 0; ch < 8; ++ch) {           // 128-col chunk
        const int nb = ch * 128;
        f32x4 acc[2][2];
#pragma unroll
        for (int i = 0; i < 2; ++i)
#pragma unroll
            for (int j = 0; j < 2; ++j) acc[i][j] = (f32x4)0.0f;

#pragma unroll
        for (int t = 0; t < 8; ++t) {          // K-tile of 128
            i32x8 af[2], bf[2];
#pragma unroll
            for (int mi = 0; mi < 2; ++mi) {
                const int row = wr2 * 32 + mi * 16 + lr;
                const i32x4 a0 = *(const i32x4*)(sA + row * 1024 +
                                                 (t * 8 + ((2 * lg + 0) ^ (row & 7))) * 16);
                const i32x4 a1 = *(const i32x4*)(sA + row * 1024 +
                                                 (t * 8 + ((2 * lg + 1) ^ (row & 7))) * 16);
                af[mi] = __builtin_shufflevector(a0, a1, 0, 1, 2, 3, 4, 5, 6, 7);
            }
#pragma unroll
            for (int nj = 0; nj < 2; ++nj) {
                const int n = nb + wc2 * 32 + nj * 16 + lr;
                const int kt16 = t * 8 + lg * 2;
                const i32x4 b0 = *(const i32x4*)(B8 + ((size_t)kt16 * N_DIM + n) * 16);
                const i32x4 b1 = *(const i32x4*)(B8 + ((size_t)(kt16 + 1) * N_DIM + n) * 16);
                bf[nj] = __builtin_shufflevector(b0, b1, 0, 1, 2, 3, 4, 5, 6, 7);
            }
#pragma unroll
            for (int mi = 0; mi < 2; ++mi)
#pragma unroll
                for (int nj = 0; nj < 2; ++nj)
                    acc[mi][nj] = __builtin_amdgcn_mfma_scale_f32_16x16x128_f8f6f4(
                        af[mi], bf[nj], acc[mi][nj], 0, 0,   // cbsz=fp8, blgp=fp8
                        0, SCALE_ONE, 0, SCALE_ONE);
        }

        // ---- store chunk: C/D layout col = lane&15, row = (lane>>4)*4 + reg ----
#pragma unroll
        for (int nj = 0; nj < 2; ++nj) {
            const int col = nb + wc2 * 32 + nj * 16 + lr;
            const float sc = scale_b[col];
#pragma unroll
            for (int mi = 0; mi < 2; ++mi) {
                const int row = m0 + wr2 * 32 + mi * 16 + lg * 4;
#pragma unroll
                for (int r = 0; r < 4; ++r) {
                    const float v = acc[mi][nj][r] * sc;
                    out[(size_t)(row + r) * N_DIM + col] = (float)(_Float16)v;
                }
            }
        }
    }
}

// ---------------- fallback: round-6 fused kernel (passing, 350 us) ----------------
__global__ __launch_bounds__(256) void gemm_fused_kernel(const float* __restrict__ A,
                                                         const float* __restrict__ W,
                                                         const float* __restrict__ scale_b,
                                                         float* __restrict__ out) {
    __shared__ __attribute__((aligned(16))) unsigned char sA[128 * 64];
    __shared__ __attribute__((aligned(16))) unsigned char sB[64 * 128];

    const int tid = threadIdx.x;
    const int l = tid & 63;
    const int wid = tid >> 6;
    const int lr = l & 15;
    const int lg = l >> 4;
    const int wr = wid >> 1;
    const int wc = wid & 1;
    const int n0 = blockIdx.x * 128;
    const int m0 = blockIdx.y * 128;

    f32x4 acc[4][4];
#pragma unroll
    for (int i = 0; i < 4; ++i)
#pragma unroll
        for (int j = 0; j < 4; ++j) acc[i][j] = (f32x4)0.0f;

    const int a_g = tid & 7;
    const int a_rb = tid >> 3;
    const int aswz = lr & 6;

    for (int kt = 0; kt < K_DIM / 64; ++kt) {
        const int k0 = kt * 64;
#pragma unroll
        for (int o = 0; o < 4; ++o) {
            const int row = o * 32 + a_rb;
            const float* ap = A + (size_t)(m0 + row) * K_DIM + k0 + a_g * 8;
            const f32x4 v0 = *(const f32x4*)ap;
            const f32x4 v1 = *(const f32x4*)(ap + 4);
            u32x2 r;
            r.x = cvt4(v0[0], v0[1], v0[2], v0[3]);
            r.y = cvt4(v1[0], v1[1], v1[2], v1[3]);
            *(u32x2*)(sA + row * 64 + ((a_g ^ (row & 6)) * 8)) = r;
        }
#pragma unroll
        for (int o = 0; o < 4; ++o) {
            const int e = o * 256 + tid;
            const int g = e >> 7;
            const int n = e & 127;
            const float* wp = W + (size_t)(k0 + g * 8) * N_DIM + n0 + n;
            float f[8];
#pragma unroll
            for (int j = 0; j < 8; ++j) f[j] = wp[(size_t)j * N_DIM];
            u32x2 r;
            r.x = cvt4(f[0], f[1], f[2], f[3]);
            r.y = cvt4(f[4], f[5], f[6], f[7]);
            *(u32x2*)(sB + g * 1024 + n * 8) = r;
        }
        __syncthreads();

#pragma unroll
        for (int kk = 0; kk < 2; ++kk) {
            long long af[4], bfr[4];
            const int gread = kk * 4 + lg;
#pragma unroll
            for (int mi = 0; mi < 4; ++mi) {
                const int m = wr * 64 + mi * 16 + lr;
                af[mi] = *(const long long*)(sA + m * 64 + ((gread ^ aswz) * 8));
            }
#pragma unroll
            for (int nj = 0; nj < 4; ++nj) {
                const int n = wc * 64 + nj * 16 + lr;
                bfr[nj] = *(const long long*)(sB + gread * 1024 + n * 8);
            }
#pragma unroll
            for (int mi = 0; mi < 4; ++mi)
#pragma unroll
                for (int nj = 0; nj < 4; ++nj)
                    acc[mi][nj] = __builtin_amdgcn_mfma_f32_16x16x32_fp8_fp8(
                        af[mi], bfr[nj], acc[mi][nj], 0, 0, 0);
        }
        __syncthreads();
    }

#pragma unroll
    for (int nj = 0; nj < 4; ++nj) {
        const int col = n0 + wc * 64 + nj * 16 + lr;
        const float sc = scale_b[col];
#pragma unroll
        for (int mi = 0; mi < 4; ++mi) {
            const int row = m0 + wr * 64 + mi * 16 + lg * 4;
#pragma unroll
            for (int r = 0; r < 4; ++r) {
                const float v = acc[mi][nj][r] * sc;
                out[(size_t)(row + r) * N_DIM + col] = (float)(_Float16)v;
            }
        }
    }
}

extern "C" void kernel_launch(void* const* d_in, const int* in_sizes, int n_in,
                              void* d_out, int out_size, void* d_ws, size_t ws_size,
                              hipStream_t stream) {
    (void)out_size;
    const void* pA = d_in[0];
    const void* pW = (n_in > 1) ? d_in[1] : d_in[0];
    const void* pS = (n_in > 2) ? d_in[2] : d_in[0];
    for (int i = 0; i < n_in && i < 3; ++i) {
        if (in_sizes[i] == M_DIM * K_DIM) pA = d_in[i];
        else if (in_sizes[i] == K_DIM * N_DIM) pW = d_in[i];
        else if (in_sizes[i] == N_DIM) pS = d_in[i];
    }
    const float* A = (const float*)pA;
    const float* W = (const float*)pW;
    const float* sb = (const float*)pS;
    float* out = (float*)d_out;

    if (ws_size >= WS_NEEDED && d_ws != nullptr) {
        unsigned char* W8 = (unsigned char*)d_ws;
        quant_w_kernel<<<256, 256, 0, stream>>>(W, W8);
        gemm_fused2_kernel<<<M_DIM / BM, 512, 0, stream>>>(A, W8, sb, out);
    } else {
        gemm_fused_kernel<<<dim3(N_DIM / 128, M_DIM / 128), 256, 0, stream>>>(A, W, sb, out);
    }
}